// Round 9
// baseline (509.906 us; speedup 1.0000x reference)
//
#include <hip/hip_runtime.h>

using u32 = unsigned int;
using u64 = unsigned long long;
using u16 = unsigned short;

typedef __attribute__((ext_vector_type(8))) short bf16x8;
typedef __attribute__((ext_vector_type(4))) float f32x4;

__device__ __forceinline__ u16 f2bf(float f) {
  u32 u = __float_as_uint(f);
  u += 0x7FFFu + ((u >> 16) & 1u);
  return (u16)(u >> 16);
}

__device__ __forceinline__ float wredMaxF(float v) {
#pragma unroll
  for (int o = 32; o > 0; o >>= 1) v = fmaxf(v, __shfl_xor(v, o, 64));
  return v;
}
__device__ __forceinline__ double wredSumD(double v) {
#pragma unroll
  for (int o = 32; o > 0; o >>= 1) v += __shfl_xor(v, o, 64);
  return v;
}

// Fast f64 exp -> f32 round. Cody-Waite reduction + degree-12 Taylor.
// rel err <= ~4e-16. Args are x <= 0 (post max-subtract).
__device__ __forceinline__ float fexpf64(double x) {
  const double INVLN2 = 1.4426950408889634074;
  const double NLN2HI = -6.93147180369123816490e-01;  // low 20 bits zero: kd*hi exact
  const double NLN2LO = -1.90821492927058770002e-10;
  double kd = rint(x * INVLN2);
  double r = fma(kd, NLN2HI, x);
  r = fma(kd, NLN2LO, r);
  double p = 2.08767569878680990e-09;   // 1/12!
  p = fma(p, r, 2.50521083854417188e-08);
  p = fma(p, r, 2.75573192239858907e-07);
  p = fma(p, r, 2.75573192239858925e-06);
  p = fma(p, r, 2.48015873015873016e-05);
  p = fma(p, r, 1.98412698412698413e-04);
  p = fma(p, r, 1.38888888888888889e-03);
  p = fma(p, r, 8.33333333333333333e-03);
  p = fma(p, r, 4.16666666666666667e-02);
  p = fma(p, r, 1.66666666666666667e-01);
  p = fma(p, r, 5.0e-01);
  p = fma(p, r, 1.0);
  p = fma(p, r, 1.0);
  int k = (int)kd;
  if (k < -1022) k = -1022;
  double s = __hiloint2double((1023 + k) << 20, 0);
  return (float)(p * s);
}

// K0: transpose qw/vw into global wT buffers (32 KB total, L2-resident).
__global__ __launch_bounds__(1024) void k_wT(
    const float* __restrict__ qw, const float* __restrict__ vw,
    float* __restrict__ wqTg, float* __restrict__ wvTg)
{
  int idx = blockIdx.x * 1024 + threadIdx.x;   // 4096 total
  int o = idx >> 6, c = idx & 63;
  wqTg[c * 64 + o] = qw[idx];
  wvTg[c * 64 + o] = vw[idx];
}

// K1 v9: FUSED q+v conv, x staged in LDS TWICE: f32 (v-path) + pre-converted
// f64 (q-path). R8 analysis: in-loop v_cvt_f64_f32 was 12 wave-cvts/c of the
// SAME wave-uniform values (768 redundant cvts/row) + AGPR shuffling at
// VGPR=36. Staging cvt = 12 wave-cvts/row total (64x fewer); in-loop reads
// are uniform-address LDS (broadcast, conflict-free, 16B/instr data-side,
// unlike R3's per-lane 1KB reads). Per-c VALU: 48(f64 fma)+24(f32 fma)=72cyc.
// xd/xf consumed pairwise to keep pressure ~55-60 VGPR (no AGPR moves).
// Numerics: xd[t]=(double)xf[t] exact, FMA order per output unchanged ->
// qs64/qs32T/vr bit-identical. LDS 36.9KB -> 4 blocks/CU.
// R7 lesson stands: q-chain must NOT be reassociated (no f64 MFMA).
__global__ __launch_bounds__(256) void k_conv_qv(
    const float* __restrict__ x, const float* __restrict__ wqTg, const float* __restrict__ qb,
    const float* __restrict__ wvTg, const float* __restrict__ vb,
    double* __restrict__ qs64, float* __restrict__ qs32T, u16* __restrict__ vr)
{
  __shared__ float Xs[4 * 768];                    // 12288 B
  __shared__ __align__(16) double Xs64[4 * 768];   // 24576 B
  const int tid = threadIdx.x;
  const int b = blockIdx.y;
  const int n0 = blockIdx.x * 4;

  // stage 4 rows x 64c x 12t: f32 copy + f64 copy (cvt once here)
#pragma unroll
  for (int j = 0; j < 3; ++j) {
    int q = tid + 256 * j;        // float4 chunk id, 768 total
    int pr = q / 3, s = q - pr * 3;
    int c = pr >> 2, nl = pr & 3;
    float4 f4 = *(const float4*)&x[(((size_t)(b * 64 + c)) * 1024 + n0 + nl) * 12 + s * 4];
    int off = nl * 768 + c * 12 + s * 4;
    *(float4*)&Xs[off] = f4;
    double2 d0, d1;
    d0.x = (double)f4.x; d0.y = (double)f4.y;
    d1.x = (double)f4.z; d1.y = (double)f4.w;
    *(double2*)&Xs64[off] = d0;
    *(double2*)&Xs64[off + 2] = d1;
  }
  __syncthreads();

  const int co = tid & 63;
  const int nl = tid >> 6;
  const float* xrow = &Xs[nl * 768];
  const double* xrow64 = &Xs64[nl * 768];

  double q0[12];
  float v0[12];
#pragma unroll
  for (int t = 0; t < 12; ++t) { q0[t] = 0.0; v0[t] = 0.f; }

#pragma unroll 2
  for (int c = 0; c < 64; ++c) {
    float wq = wqTg[c * 64 + co];   // coalesced 256B wave read, L2-resident
    float wv = wvTg[c * 64 + co];
    double wqd = (double)wq;
    // v-path: 3 uniform float4 reads, consumed immediately
#pragma unroll
    for (int s = 0; s < 3; ++s) {
      float4 xf4 = *(const float4*)&xrow[c * 12 + 4 * s];
      v0[4 * s + 0] += wv * xf4.x;
      v0[4 * s + 1] += wv * xf4.y;
      v0[4 * s + 2] += wv * xf4.z;
      v0[4 * s + 3] += wv * xf4.w;
    }
    // q-path: 6 uniform double2 reads, consumed immediately (no cvt in loop)
#pragma unroll
    for (int k = 0; k < 6; ++k) {
      double2 xd2 = *(const double2*)&xrow64[c * 12 + 2 * k];
      q0[2 * k + 0] = fma(wqd, xd2.x, q0[2 * k + 0]);
      q0[2 * k + 1] = fma(wqd, xd2.y, q0[2 * k + 1]);
    }
  }

  const float qbv = qb[co];
  const float vbv = vb[co];
  double sA = 0.0;
#pragma unroll
  for (int t = 0; t < 12; ++t) {
    float qa = fmaxf((float)q0[t] + qbv, 0.f);
    sA += (double)qa;
  }
  const int n = n0 + nl;
  qs64[((size_t)(b * 1024 + n)) * 64 + co] = sA;
  qs32T[((size_t)(b * 64 + co)) * 1024 + n] = (float)sA;

  size_t vb0 = ((size_t)(b * 1024 + n)) * 768 + co * 12;
#pragma unroll
  for (int i = 0; i < 6; ++i) {
    u32 p0 = (u32)f2bf(fmaxf(v0[2 * i] + vbv, 0.f)) | ((u32)f2bf(fmaxf(v0[2 * i + 1] + vbv, 0.f)) << 16);
    *(u32*)&vr[vb0 + 2 * i] = p0;
  }
}

// K1c: vr[b][m][ct] -> vrT[b][ct][m]
__global__ __launch_bounds__(256) void k_transpose_vr(const u16* __restrict__ vr, u16* __restrict__ vrT)
{
  __shared__ u16 Tt[64 * 72];
  const int tid = threadIdx.x;
  const int b = blockIdx.z;
  const int ct0 = blockIdx.x * 64;
  const int m0 = blockIdx.y * 64;
#pragma unroll
  for (int j = 0; j < 2; ++j) {
    int idx = tid + 256 * j;
    int r = idx >> 3, s = idx & 7;
    u16 tmp[8];
    *(uint4*)tmp = *(const uint4*)&vr[((size_t)(b * 1024 + m0 + r)) * 768 + ct0 + s * 8];
#pragma unroll
    for (int jj = 0; jj < 8; ++jj) Tt[(s * 8 + jj) * 72 + r] = tmp[jj];
  }
  __syncthreads();
#pragma unroll
  for (int j = 0; j < 2; ++j) {
    int idx = tid + 256 * j;
    int r2 = idx >> 3, s2 = idx & 7;
    *(uint4*)&vrT[((size_t)(b * 768 + ct0 + r2)) * 1024 + m0 + s2 * 8] =
        *(const uint4*)&Tt[r2 * 72 + s2 * 8];
  }
}

// K2 v3: f64-accumulate scores, fma chain over c globally ascending — bit-identical
// S1/S2. Bm/Bq staged as f64 in LDS (cvt once at staging). Skewed layout
// c*80 + mgi*10 + k doubles: conflict-free. LDS 37.9 KB -> 4 blocks/CU.
__global__ __launch_bounds__(256) void k_score(
    const double* __restrict__ qs64, const float* __restrict__ qs32T, const float* __restrict__ mem,
    float* __restrict__ S1, float* __restrict__ S2, int b0)
{
  __shared__ __align__(16) double As64[128 * 17];   // 17408 B
  __shared__ __align__(16) double Bm64[16 * 80];    // 10240 B
  __shared__ __align__(16) double Bq64[16 * 80];    // 10240 B
  const int tid = threadIdx.x;
  const int g = blockIdx.z;
  const int b = b0 + g;
  const int m0 = blockIdx.x * 64;
  const int n0 = blockIdx.y * 128;

  const int mgi  = tid & 7;    // m = m0 + mgi*8 + k
  const int ngrp = tid >> 3;   // n = n0 + ngrp*4 + ni

  double acc1[4][8], acc2[4][8];
#pragma unroll
  for (int i = 0; i < 4; ++i)
#pragma unroll
    for (int k = 0; k < 8; ++k) { acc1[i][k] = 0.0; acc2[i][k] = 0.0; }

  for (int ph = 0; ph < 4; ++ph) {
    const int cb = ph * 16;
    __syncthreads();
#pragma unroll
    for (int j = 0; j < 8; ++j) {
      int idx = tid + 256 * j;
      int nl = idx >> 4, c = idx & 15;
      As64[nl * 17 + c] = qs64[((size_t)(b * 1024 + n0 + nl)) * 64 + cb + c];
    }
#pragma unroll
    for (int j = 0; j < 4; ++j) {
      int idx = tid + 256 * j;
      int c = idx >> 6, mm = idx & 63;
      float fm = mem[(size_t)(cb + c) * 1024 + m0 + mm];
      float fq = qs32T[((size_t)(b * 64 + cb + c)) * 1024 + m0 + mm];
      int off = c * 80 + (mm >> 3) * 10 + (mm & 7);
      Bm64[off] = (double)fm;
      Bq64[off] = (double)fq;
    }
    __syncthreads();

    for (int c = 0; c < 16; ++c) {
      double a[4], af[4];
#pragma unroll
      for (int i = 0; i < 4; ++i) {
        a[i] = As64[(ngrp * 4 + i) * 17 + c];
        af[i] = (double)(float)a[i];   // == np's f32 qs, bit-exact
      }
      const double* pm = &Bm64[c * 80 + mgi * 10];
      const double* pq = &Bq64[c * 80 + mgi * 10];
#pragma unroll
      for (int kh = 0; kh < 2; ++kh) {   // k-halved: caps live bm/bq at 16 regs
        double bm[4], bq[4];
#pragma unroll
        for (int k = 0; k < 2; ++k) {
          *(double2*)&bm[2 * k] = *(const double2*)&pm[4 * kh + 2 * k];
          *(double2*)&bq[2 * k] = *(const double2*)&pq[4 * kh + 2 * k];
        }
#pragma unroll
        for (int k = 0; k < 4; ++k) {
#pragma unroll
          for (int i = 0; i < 4; ++i) {
            acc1[i][4 * kh + k] = fma(a[i], bm[k], acc1[i][4 * kh + k]);
            acc2[i][4 * kh + k] = fma(af[i], bq[k], acc2[i][4 * kh + k]);
          }
        }
      }
    }
  }
#pragma unroll
  for (int ni = 0; ni < 4; ++ni) {
    size_t off = ((size_t)g * 1024 + n0 + ngrp * 4 + ni) * 1024 + m0 + mgi * 8;
    float o1[8], o2[8];
#pragma unroll
    for (int k = 0; k < 8; ++k) {
      o1[k] = fmaxf((float)(0.125 * acc1[ni][k]), 0.f);
      o2[k] = fmaxf((float)(0.125 * acc2[ni][k]), 0.f);
    }
    *(float4*)&S1[off + 0] = *(float4*)&o1[0];
    *(float4*)&S1[off + 4] = *(float4*)&o1[4];
    *(float4*)&S2[off + 0] = *(float4*)&o2[0];
    *(float4*)&S2[off + 4] = *(float4*)&o2[4];
  }
}

// K3: wave-per-row row chain. 4 rows/block, one 64-lane wave each, no LDS.
__global__ __launch_bounds__(256) void k_row(
    const float* __restrict__ S1, const float* __restrict__ S2,
    const float* __restrict__ fc1w, const float* __restrict__ fc1b,
    const float* __restrict__ fc2w, const float* __restrict__ fc2b,
    u16* __restrict__ adj, int b0)
{
  const int tid = threadIdx.x;
  const int wv = tid >> 6;
  const int lane = tid & 63;
  const int n = blockIdx.x * 4 + wv;
  const int g = blockIdx.y;

  float w10[8], w11[8], b1s[8], w2s[8];
#pragma unroll
  for (int h = 0; h < 8; ++h) {
    w10[h] = fc1w[2 * h];
    w11[h] = fc1w[2 * h + 1];
    b1s[h] = fc1b[h];
    w2s[h] = fc2w[h];
  }
  const float b2s = fc2b[0];

  const float* r1 = S1 + ((size_t)g * 1024 + n) * 1024;
  const float* r2 = S2 + ((size_t)g * 1024 + n) * 1024;
  const int e0 = lane * 16;
  float s1v[16], s2v[16];
#pragma unroll
  for (int k = 0; k < 4; ++k) {
    *(float4*)&s1v[4 * k] = *(const float4*)&r1[e0 + 4 * k];
    *(float4*)&s2v[4 * k] = *(const float4*)&r2[e0 + 4 * k];
  }

  float lm1 = s1v[0], lm2 = s2v[0];
#pragma unroll
  for (int j = 1; j < 16; ++j) { lm1 = fmaxf(lm1, s1v[j]); lm2 = fmaxf(lm2, s2v[j]); }
  const float m1 = wredMaxF(lm1);
  const float m2 = wredMaxF(lm2);

  float e1[16], e2[16];
  double ls1 = 0.0, ls2 = 0.0;
#pragma unroll
  for (int j = 0; j < 16; ++j) {
    e1[j] = fexpf64((double)(s1v[j] - m1));
    ls1 += (double)e1[j];
    e2[j] = fexpf64((double)(s2v[j] - m2));
    ls2 += (double)e2[j];
  }
  const float Z1f = (float)wredSumD(ls1);
  const float Z2f = (float)wredSumD(ls2);

  float zv[16];
#pragma unroll
  for (int j = 0; j < 16; ++j) {
    float a1 = e1[j] / Z1f;
    float a2 = e2[j] / Z2f;
    float acc = 0.f;
#pragma unroll
    for (int h = 0; h < 8; ++h) {
      float hp = __fmaf_rn(a2, w11[h], __fmaf_rn(a1, w10[h], 0.0f));
      hp = hp + b1s[h];
      float hr = fmaxf(hp, 0.f);
      acc = __fmaf_rn(hr, w2s[h], acc);
    }
    zv[j] = acc + b2s;
  }

  float lmz = zv[0];
#pragma unroll
  for (int j = 1; j < 16; ++j) lmz = fmaxf(lmz, zv[j]);
  const float mz = wredMaxF(lmz);
  float ez[16];
  double lsz = 0.0;
#pragma unroll
  for (int j = 0; j < 16; ++j) {
    ez[j] = fexpf64((double)(zv[j] - mz));
    lsz += (double)ez[j];
  }
  const float Zzf = (float)wredSumD(lsz);

  u32 kreg[16];
#pragma unroll
  for (int j = 0; j < 16; ++j) kreg[j] = __float_as_uint(ez[j] / Zzf);

  // exact 819th-largest via bitwise binary search (keys >= 0: uint order == float order)
  u32 vkey = 0u;
  for (int bit = 30; bit >= 0; --bit) {
    u32 cand = vkey | (1u << bit);
    u32 cnt = 0u;
#pragma unroll
    for (int j = 0; j < 16; ++j)
      cnt += (u32)__popcll(__ballot(kreg[j] >= cand));
    if (cnt >= 819u) vkey = cand;
  }
  u32 cntGT = 0u;
#pragma unroll
  for (int j = 0; j < 16; ++j)
    cntGT += (u32)__popcll(__ballot(kreg[j] > vkey));
  const u32 need_eq = 819u - cntGT;

  int cnt = 0;
#pragma unroll
  for (int j = 0; j < 16; ++j) cnt += (kreg[j] == vkey) ? 1 : 0;
  u32 inc = (u32)cnt;
#pragma unroll
  for (int o = 1; o < 64; o <<= 1) {
    u32 nv = __shfl_up(inc, o, 64);
    if (lane >= o) inc += nv;
  }
  u32 run = inc - (u32)cnt;

  u16 ov[16];
#pragma unroll
  for (int j = 0; j < 16; ++j) {
    u32 kk = kreg[j];
    bool eq = (kk == vkey);
    bool keep = (kk > vkey) || (eq && (run < need_eq));
    if (eq) run += 1u;
    ov[j] = keep ? f2bf(__uint_as_float(kk)) : (u16)0;
  }
  u16* arow = adj + ((size_t)(b0 + g) * 1024 + n) * 1024 + e0;
  *(uint4*)&arow[0] = *(uint4*)&ov[0];
  *(uint4*)&arow[8] = *(uint4*)&ov[8];
}

// K4: agg = adj @ vr, bf16 MFMA 16x16x32, 128x128 tile, BK=32 (R3 version)
__global__ __launch_bounds__(256) void k_gemm_agg(
    const u16* __restrict__ adj, const u16* __restrict__ vrT, float* __restrict__ agg)
{
  __shared__ u16 As[128 * 40];
  __shared__ u16 Bs[128 * 40];
  const int tid = threadIdx.x;
  const int b = blockIdx.z;
  const int n0 = blockIdx.y * 128;
  const int ct0 = blockIdx.x * 128;
  const int wid = tid >> 6;
  const int lane = tid & 63;
  const int l16 = lane & 15;
  const int quad = lane >> 4;
  const int wm = (wid >> 1) * 64;
  const int wn = (wid & 1) * 64;

  f32x4 acc[4][4];
#pragma unroll
  for (int i = 0; i < 4; ++i)
#pragma unroll
    for (int j = 0; j < 4; ++j) acc[i][j] = (f32x4)0.f;

  const u16* aG = adj + ((size_t)b * 1024 + n0) * 1024;
  const u16* bG = vrT + ((size_t)b * 768 + ct0) * 1024;

  for (int kt = 0; kt < 32; ++kt) {
    const int k0 = kt * 32;
    __syncthreads();
#pragma unroll
    for (int j = 0; j < 2; ++j) {
      int idx = tid + 256 * j;
      int row = idx >> 2, seg = idx & 3;
      *(uint4*)&As[row * 40 + seg * 8] = *(const uint4*)&aG[(size_t)row * 1024 + k0 + seg * 8];
      *(uint4*)&Bs[row * 40 + seg * 8] = *(const uint4*)&bG[(size_t)row * 1024 + k0 + seg * 8];
    }
    __syncthreads();
    bf16x8 af[4], bfv[4];
#pragma unroll
    for (int i = 0; i < 4; ++i) af[i] = *(bf16x8*)&As[(wm + i * 16 + l16) * 40 + quad * 8];
#pragma unroll
    for (int j = 0; j < 4; ++j) bfv[j] = *(bf16x8*)&Bs[(wn + j * 16 + l16) * 40 + quad * 8];
#pragma unroll
    for (int i = 0; i < 4; ++i)
#pragma unroll
      for (int j = 0; j < 4; ++j)
        acc[i][j] = __builtin_amdgcn_mfma_f32_16x16x32_bf16(af[i], bfv[j], acc[i][j], 0, 0, 0);
  }

#pragma unroll
  for (int i = 0; i < 4; ++i)
#pragma unroll
    for (int j = 0; j < 4; ++j)
#pragma unroll
      for (int r = 0; r < 4; ++r) {
        int row = n0 + wm + i * 16 + quad * 4 + r;
        int col = ct0 + wn + j * 16 + l16;
        agg[((size_t)b * 1024 + row) * 768 + col] = acc[i][j][r];
      }
}

// K5: out = relu(conv_c(agg)), fp32
__global__ __launch_bounds__(256) void k_convc(
    const float* __restrict__ agg, const float* __restrict__ cw,
    const float* __restrict__ cb, float* __restrict__ out)
{
  __shared__ float aggL[16 * 388];
  __shared__ float cwT[64 * 68];
  __shared__ float cbL[64];
  const int tid = threadIdx.x;
  const int b = blockIdx.y;
  const int n0 = blockIdx.x * 16;

#pragma unroll
  for (int j = 0; j < 16; ++j) {
    int idx = tid + 256 * j;
    int o = idx >> 6, c = idx & 63;
    cwT[c * 68 + o] = cw[idx];
  }
  if (tid < 64) cbL[tid] = cb[tid];

  const int o0 = (tid & 15) * 4;
  const int nl = tid >> 4;
  float acc[4][12];
#pragma unroll
  for (int oo = 0; oo < 4; ++oo)
#pragma unroll
    for (int t = 0; t < 12; ++t) acc[oo][t] = 0.f;

  for (int ph = 0; ph < 2; ++ph) {
    __syncthreads();
#pragma unroll
    for (int j = 0; j < 6; ++j) {
      int q4 = tid + 256 * j;
      int row = q4 / 96, wi = q4 - row * 96;
      *(float4*)&aggL[row * 388 + wi * 4] =
          *(const float4*)&agg[((size_t)(b * 1024 + n0 + row)) * 768 + ph * 384 + wi * 4];
    }
    __syncthreads();
    for (int cc = 0; cc < 32; ++cc) {
      int c = ph * 32 + cc;
      float4 w4 = *(float4*)&cwT[c * 68 + o0];
      float xr[12];
      *(float4*)&xr[0] = *(float4*)&aggL[nl * 388 + cc * 12 + 0];
      *(float4*)&xr[4] = *(float4*)&aggL[nl * 388 + cc * 12 + 4];
      *(float4*)&xr[8] = *(float4*)&aggL[nl * 388 + cc * 12 + 8];
#pragma unroll
      for (int t = 0; t < 12; ++t) {
        acc[0][t] += w4.x * xr[t];
        acc[1][t] += w4.y * xr[t];
        acc[2][t] += w4.z * xr[t];
        acc[3][t] += w4.w * xr[t];
      }
    }
  }

#pragma unroll
  for (int oo = 0; oo < 4; ++oo) {
    int o = o0 + oo;
    float bias = cbL[o];
    float ovv[12];
#pragma unroll
    for (int t = 0; t < 12; ++t) ovv[t] = fmaxf(acc[oo][t] + bias, 0.f);
    size_t base = ((size_t)(b * 64 + o) * 1024 + n0 + nl) * 12;
    *(float4*)&out[base + 0] = *(float4*)&ovv[0];
    *(float4*)&out[base + 4] = *(float4*)&ovv[4];
    *(float4*)&out[base + 8] = *(float4*)&ovv[8];
  }
}

extern "C" void kernel_launch(void* const* d_in, const int* in_sizes, int n_in,
                              void* d_out, int out_size, void* d_ws, size_t ws_size,
                              hipStream_t stream)
{
  const float* x    = (const float*)d_in[0];
  const float* qw   = (const float*)d_in[1];
  const float* qb   = (const float*)d_in[2];
  const float* vw   = (const float*)d_in[3];
  const float* vb   = (const float*)d_in[4];
  const float* cw   = (const float*)d_in[5];
  const float* cb   = (const float*)d_in[6];
  const float* mem  = (const float*)d_in[7];
  const float* fc1w = (const float*)d_in[8];
  const float* fc1b = (const float*)d_in[9];
  const float* fc2w = (const float*)d_in[10];
  const float* fc2b = (const float*)d_in[11];
  float* out = (float*)d_out;
  char* ws = (char*)d_ws;

  const size_t szQS64  = (size_t)16 * 1024 * 64 * 8;   // 8 MB
  const size_t szQS32T = (size_t)16 * 1024 * 64 * 4;   // 4 MB
  const size_t szVR    = (size_t)16 * 1024 * 768 * 2;  // 24 MB
  const size_t szADJ   = (size_t)16 * 1024 * 1024 * 2; // 32 MB
  const size_t szAGG   = (size_t)16 * 1024 * 768 * 4;  // 48 MB
  const size_t szWT    = (size_t)2 * 64 * 64 * 4;      // 32 KB (wqT + wvT)
  const size_t szSb    = (size_t)1024 * 1024 * 4;      // one f32 S matrix, one batch
  const size_t fixed   = szQS64 + szQS32T + 2 * szVR + szADJ + szAGG + szWT;

  int G = 16;
  while (G > 1 && (fixed + (size_t)2 * G * szSb) > ws_size) G >>= 1;

  double* qs64  = (double*)(ws);
  float*  qs32T = (float*)(ws + szQS64);
  u16*  vr      = (u16*)(ws + szQS64 + szQS32T);
  u16*  vrT     = (u16*)(ws + szQS64 + szQS32T + szVR);
  u16*  adj     = (u16*)(ws + szQS64 + szQS32T + 2 * szVR);
  float* agg    = (float*)(ws + szQS64 + szQS32T + 2 * szVR + szADJ);
  float* wqTg   = (float*)(ws + szQS64 + szQS32T + 2 * szVR + szADJ + szAGG);
  float* wvTg   = wqTg + 64 * 64;
  float* S1     = (float*)(ws + fixed);
  float* S2     = S1 + (size_t)G * 1024 * 1024;

  hipLaunchKernelGGL(k_wT, dim3(4), dim3(1024), 0, stream, qw, vw, wqTg, wvTg);
  hipLaunchKernelGGL(k_conv_qv, dim3(256, 16), dim3(256), 0, stream, x, wqTg, qb, wvTg, vb, qs64, qs32T, vr);
  hipLaunchKernelGGL(k_transpose_vr, dim3(12, 16, 16), dim3(256), 0, stream, vr, vrT);
  for (int b0 = 0; b0 < 16; b0 += G) {
    hipLaunchKernelGGL(k_score, dim3(16, 8, G), dim3(256), 0, stream, qs64, qs32T, mem, S1, S2, b0);
    hipLaunchKernelGGL(k_row, dim3(256, G), dim3(256), 0, stream, S1, S2, fc1w, fc1b, fc2w, fc2b, adj, b0);
  }
  hipLaunchKernelGGL(k_gemm_agg, dim3(6, 8, 16), dim3(256), 0, stream, adj, vrT, agg);
  hipLaunchKernelGGL(k_convc, dim3(64, 16), dim3(256), 0, stream, agg, cw, cb, out);
}

// Round 10
// 490.466 us; speedup vs baseline: 1.0396x; 1.0396x over previous
//
#include <hip/hip_runtime.h>

using u32 = unsigned int;
using u64 = unsigned long long;
using u16 = unsigned short;

typedef __attribute__((ext_vector_type(8))) short bf16x8;
typedef __attribute__((ext_vector_type(4))) float f32x4;

__device__ __forceinline__ u16 f2bf(float f) {
  u32 u = __float_as_uint(f);
  u += 0x7FFFu + ((u >> 16) & 1u);
  return (u16)(u >> 16);
}

__device__ __forceinline__ float wredMaxF(float v) {
#pragma unroll
  for (int o = 32; o > 0; o >>= 1) v = fmaxf(v, __shfl_xor(v, o, 64));
  return v;
}
__device__ __forceinline__ double wredSumD(double v) {
#pragma unroll
  for (int o = 32; o > 0; o >>= 1) v += __shfl_xor(v, o, 64);
  return v;
}

// Fast f64 exp -> f32 round. Cody-Waite reduction + degree-12 Taylor.
// rel err <= ~4e-16. Args are x <= 0 (post max-subtract).
__device__ __forceinline__ float fexpf64(double x) {
  const double INVLN2 = 1.4426950408889634074;
  const double NLN2HI = -6.93147180369123816490e-01;  // low 20 bits zero: kd*hi exact
  const double NLN2LO = -1.90821492927058770002e-10;
  double kd = rint(x * INVLN2);
  double r = fma(kd, NLN2HI, x);
  r = fma(kd, NLN2LO, r);
  double p = 2.08767569878680990e-09;   // 1/12!
  p = fma(p, r, 2.50521083854417188e-08);
  p = fma(p, r, 2.75573192239858907e-07);
  p = fma(p, r, 2.75573192239858925e-06);
  p = fma(p, r, 2.48015873015873016e-05);
  p = fma(p, r, 1.98412698412698413e-04);
  p = fma(p, r, 1.38888888888888889e-03);
  p = fma(p, r, 8.33333333333333333e-03);
  p = fma(p, r, 4.16666666666666667e-02);
  p = fma(p, r, 1.66666666666666667e-01);
  p = fma(p, r, 5.0e-01);
  p = fma(p, r, 1.0);
  p = fma(p, r, 1.0);
  int k = (int)kd;
  if (k < -1022) k = -1022;
  double s = __hiloint2double((1023 + k) << 20, 0);
  return (float)(p * s);
}

// K0: transpose qw/vw into global wT buffers (32 KB total, L2-resident).
__global__ __launch_bounds__(1024) void k_wT(
    const float* __restrict__ qw, const float* __restrict__ vw,
    float* __restrict__ wqTg, float* __restrict__ wvTg)
{
  int idx = blockIdx.x * 1024 + threadIdx.x;   // 4096 total
  int o = idx >> 6, c = idx & 63;
  wqTg[c * 64 + o] = qw[idx];
  wvTg[c * 64 + o] = vw[idx];
}

// K1 v10: R8 inner loop (best-measured: f32 LDS + in-loop cvt, VALU-bound)
// with structural fixes only: 512-thread blocks / 8 rows (2048 blocks, half
// the dispatch churn of 4096) and unroll 4 (batches the per-c weight loads
// for L2-latency hiding). R9 lesson: f64 pre-staging trades VALU for LDS-issue
// (9 LDS ops/c) and loses occupancy — reverted. Numerics byte-identical to
// R6/R8 (same expressions, same c-ascending order) -> qs64/qs32T/vr bit-exact.
// R7 lesson stands: q-chain must NOT be reassociated.
__global__ __launch_bounds__(512) void k_conv_qv(
    const float* __restrict__ x, const float* __restrict__ wqTg, const float* __restrict__ qb,
    const float* __restrict__ wvTg, const float* __restrict__ vb,
    double* __restrict__ qs64, float* __restrict__ qs32T, u16* __restrict__ vr)
{
  __shared__ float Xs[8 * 768];   // 24576 B
  const int tid = threadIdx.x;
  const int b = blockIdx.y;
  const int n0 = blockIdx.x * 8;

  // stage 8 rows x 64c x 12t
#pragma unroll
  for (int j = 0; j < 3; ++j) {
    int q = tid + 512 * j;        // float4 chunk id, 1536 total
    int pr = q / 3, s = q - pr * 3;
    int c = pr >> 3, nl = pr & 7;
    *(float4*)&Xs[nl * 768 + c * 12 + s * 4] =
        *(const float4*)&x[(((size_t)(b * 64 + c)) * 1024 + n0 + nl) * 12 + s * 4];
  }
  __syncthreads();

  const int co = tid & 63;
  const int nl = tid >> 6;
  const float* xrow = &Xs[nl * 768];

  double q0[12];
  float v0[12];
#pragma unroll
  for (int t = 0; t < 12; ++t) { q0[t] = 0.0; v0[t] = 0.f; }

#pragma unroll 4
  for (int c = 0; c < 64; ++c) {
    float wq = wqTg[c * 64 + co];   // coalesced 256B wave read, L2-resident
    float wv = wvTg[c * 64 + co];
    float xf[12];
    *(float4*)&xf[0] = *(const float4*)&xrow[c * 12 + 0];
    *(float4*)&xf[4] = *(const float4*)&xrow[c * 12 + 4];
    *(float4*)&xf[8] = *(const float4*)&xrow[c * 12 + 8];
    double wqd = (double)wq;
#pragma unroll
    for (int t = 0; t < 12; ++t) {
      q0[t] = fma(wqd, (double)xf[t], q0[t]);
      v0[t] += wv * xf[t];
    }
  }

  const float qbv = qb[co];
  const float vbv = vb[co];
  double sA = 0.0;
#pragma unroll
  for (int t = 0; t < 12; ++t) {
    float qa = fmaxf((float)q0[t] + qbv, 0.f);
    sA += (double)qa;
  }
  const int n = n0 + nl;
  qs64[((size_t)(b * 1024 + n)) * 64 + co] = sA;
  qs32T[((size_t)(b * 64 + co)) * 1024 + n] = (float)sA;

  size_t vb0 = ((size_t)(b * 1024 + n)) * 768 + co * 12;
#pragma unroll
  for (int i = 0; i < 6; ++i) {
    u32 p0 = (u32)f2bf(fmaxf(v0[2 * i] + vbv, 0.f)) | ((u32)f2bf(fmaxf(v0[2 * i + 1] + vbv, 0.f)) << 16);
    *(u32*)&vr[vb0 + 2 * i] = p0;
  }
}

// K1c: vr[b][m][ct] -> vrT[b][ct][m]
__global__ __launch_bounds__(256) void k_transpose_vr(const u16* __restrict__ vr, u16* __restrict__ vrT)
{
  __shared__ u16 Tt[64 * 72];
  const int tid = threadIdx.x;
  const int b = blockIdx.z;
  const int ct0 = blockIdx.x * 64;
  const int m0 = blockIdx.y * 64;
#pragma unroll
  for (int j = 0; j < 2; ++j) {
    int idx = tid + 256 * j;
    int r = idx >> 3, s = idx & 7;
    u16 tmp[8];
    *(uint4*)tmp = *(const uint4*)&vr[((size_t)(b * 1024 + m0 + r)) * 768 + ct0 + s * 8];
#pragma unroll
    for (int jj = 0; jj < 8; ++jj) Tt[(s * 8 + jj) * 72 + r] = tmp[jj];
  }
  __syncthreads();
#pragma unroll
  for (int j = 0; j < 2; ++j) {
    int idx = tid + 256 * j;
    int r2 = idx >> 3, s2 = idx & 7;
    *(uint4*)&vrT[((size_t)(b * 768 + ct0 + r2)) * 1024 + m0 + s2 * 8] =
        *(const uint4*)&Tt[r2 * 72 + s2 * 8];
  }
}

// K2 v3: f64-accumulate scores, fma chain over c globally ascending — bit-identical
// S1/S2. Bm/Bq staged as f64 in LDS (cvt once at staging). Skewed layout
// c*80 + mgi*10 + k doubles: conflict-free. LDS 37.9 KB -> 4 blocks/CU.
__global__ __launch_bounds__(256) void k_score(
    const double* __restrict__ qs64, const float* __restrict__ qs32T, const float* __restrict__ mem,
    float* __restrict__ S1, float* __restrict__ S2, int b0)
{
  __shared__ __align__(16) double As64[128 * 17];   // 17408 B
  __shared__ __align__(16) double Bm64[16 * 80];    // 10240 B
  __shared__ __align__(16) double Bq64[16 * 80];    // 10240 B
  const int tid = threadIdx.x;
  const int g = blockIdx.z;
  const int b = b0 + g;
  const int m0 = blockIdx.x * 64;
  const int n0 = blockIdx.y * 128;

  const int mgi  = tid & 7;    // m = m0 + mgi*8 + k
  const int ngrp = tid >> 3;   // n = n0 + ngrp*4 + ni

  double acc1[4][8], acc2[4][8];
#pragma unroll
  for (int i = 0; i < 4; ++i)
#pragma unroll
    for (int k = 0; k < 8; ++k) { acc1[i][k] = 0.0; acc2[i][k] = 0.0; }

  for (int ph = 0; ph < 4; ++ph) {
    const int cb = ph * 16;
    __syncthreads();
#pragma unroll
    for (int j = 0; j < 8; ++j) {
      int idx = tid + 256 * j;
      int nl = idx >> 4, c = idx & 15;
      As64[nl * 17 + c] = qs64[((size_t)(b * 1024 + n0 + nl)) * 64 + cb + c];
    }
#pragma unroll
    for (int j = 0; j < 4; ++j) {
      int idx = tid + 256 * j;
      int c = idx >> 6, mm = idx & 63;
      float fm = mem[(size_t)(cb + c) * 1024 + m0 + mm];
      float fq = qs32T[((size_t)(b * 64 + cb + c)) * 1024 + m0 + mm];
      int off = c * 80 + (mm >> 3) * 10 + (mm & 7);
      Bm64[off] = (double)fm;
      Bq64[off] = (double)fq;
    }
    __syncthreads();

    for (int c = 0; c < 16; ++c) {
      double a[4], af[4];
#pragma unroll
      for (int i = 0; i < 4; ++i) {
        a[i] = As64[(ngrp * 4 + i) * 17 + c];
        af[i] = (double)(float)a[i];   // == np's f32 qs, bit-exact
      }
      const double* pm = &Bm64[c * 80 + mgi * 10];
      const double* pq = &Bq64[c * 80 + mgi * 10];
#pragma unroll
      for (int kh = 0; kh < 2; ++kh) {   // k-halved: caps live bm/bq at 16 regs
        double bm[4], bq[4];
#pragma unroll
        for (int k = 0; k < 2; ++k) {
          *(double2*)&bm[2 * k] = *(const double2*)&pm[4 * kh + 2 * k];
          *(double2*)&bq[2 * k] = *(const double2*)&pq[4 * kh + 2 * k];
        }
#pragma unroll
        for (int k = 0; k < 4; ++k) {
#pragma unroll
          for (int i = 0; i < 4; ++i) {
            acc1[i][4 * kh + k] = fma(a[i], bm[k], acc1[i][4 * kh + k]);
            acc2[i][4 * kh + k] = fma(af[i], bq[k], acc2[i][4 * kh + k]);
          }
        }
      }
    }
  }
#pragma unroll
  for (int ni = 0; ni < 4; ++ni) {
    size_t off = ((size_t)g * 1024 + n0 + ngrp * 4 + ni) * 1024 + m0 + mgi * 8;
    float o1[8], o2[8];
#pragma unroll
    for (int k = 0; k < 8; ++k) {
      o1[k] = fmaxf((float)(0.125 * acc1[ni][k]), 0.f);
      o2[k] = fmaxf((float)(0.125 * acc2[ni][k]), 0.f);
    }
    *(float4*)&S1[off + 0] = *(float4*)&o1[0];
    *(float4*)&S1[off + 4] = *(float4*)&o1[4];
    *(float4*)&S2[off + 0] = *(float4*)&o2[0];
    *(float4*)&S2[off + 4] = *(float4*)&o2[4];
  }
}

// K3: wave-per-row row chain. 4 rows/block, one 64-lane wave each, no LDS.
__global__ __launch_bounds__(256) void k_row(
    const float* __restrict__ S1, const float* __restrict__ S2,
    const float* __restrict__ fc1w, const float* __restrict__ fc1b,
    const float* __restrict__ fc2w, const float* __restrict__ fc2b,
    u16* __restrict__ adj, int b0)
{
  const int tid = threadIdx.x;
  const int wv = tid >> 6;
  const int lane = tid & 63;
  const int n = blockIdx.x * 4 + wv;
  const int g = blockIdx.y;

  float w10[8], w11[8], b1s[8], w2s[8];
#pragma unroll
  for (int h = 0; h < 8; ++h) {
    w10[h] = fc1w[2 * h];
    w11[h] = fc1w[2 * h + 1];
    b1s[h] = fc1b[h];
    w2s[h] = fc2w[h];
  }
  const float b2s = fc2b[0];

  const float* r1 = S1 + ((size_t)g * 1024 + n) * 1024;
  const float* r2 = S2 + ((size_t)g * 1024 + n) * 1024;
  const int e0 = lane * 16;
  float s1v[16], s2v[16];
#pragma unroll
  for (int k = 0; k < 4; ++k) {
    *(float4*)&s1v[4 * k] = *(const float4*)&r1[e0 + 4 * k];
    *(float4*)&s2v[4 * k] = *(const float4*)&r2[e0 + 4 * k];
  }

  float lm1 = s1v[0], lm2 = s2v[0];
#pragma unroll
  for (int j = 1; j < 16; ++j) { lm1 = fmaxf(lm1, s1v[j]); lm2 = fmaxf(lm2, s2v[j]); }
  const float m1 = wredMaxF(lm1);
  const float m2 = wredMaxF(lm2);

  float e1[16], e2[16];
  double ls1 = 0.0, ls2 = 0.0;
#pragma unroll
  for (int j = 0; j < 16; ++j) {
    e1[j] = fexpf64((double)(s1v[j] - m1));
    ls1 += (double)e1[j];
    e2[j] = fexpf64((double)(s2v[j] - m2));
    ls2 += (double)e2[j];
  }
  const float Z1f = (float)wredSumD(ls1);
  const float Z2f = (float)wredSumD(ls2);

  float zv[16];
#pragma unroll
  for (int j = 0; j < 16; ++j) {
    float a1 = e1[j] / Z1f;
    float a2 = e2[j] / Z2f;
    float acc = 0.f;
#pragma unroll
    for (int h = 0; h < 8; ++h) {
      float hp = __fmaf_rn(a2, w11[h], __fmaf_rn(a1, w10[h], 0.0f));
      hp = hp + b1s[h];
      float hr = fmaxf(hp, 0.f);
      acc = __fmaf_rn(hr, w2s[h], acc);
    }
    zv[j] = acc + b2s;
  }

  float lmz = zv[0];
#pragma unroll
  for (int j = 1; j < 16; ++j) lmz = fmaxf(lmz, zv[j]);
  const float mz = wredMaxF(lmz);
  float ez[16];
  double lsz = 0.0;
#pragma unroll
  for (int j = 0; j < 16; ++j) {
    ez[j] = fexpf64((double)(zv[j] - mz));
    lsz += (double)ez[j];
  }
  const float Zzf = (float)wredSumD(lsz);

  u32 kreg[16];
#pragma unroll
  for (int j = 0; j < 16; ++j) kreg[j] = __float_as_uint(ez[j] / Zzf);

  // exact 819th-largest via bitwise binary search (keys >= 0: uint order == float order)
  u32 vkey = 0u;
  for (int bit = 30; bit >= 0; --bit) {
    u32 cand = vkey | (1u << bit);
    u32 cnt = 0u;
#pragma unroll
    for (int j = 0; j < 16; ++j)
      cnt += (u32)__popcll(__ballot(kreg[j] >= cand));
    if (cnt >= 819u) vkey = cand;
  }
  u32 cntGT = 0u;
#pragma unroll
  for (int j = 0; j < 16; ++j)
    cntGT += (u32)__popcll(__ballot(kreg[j] > vkey));
  const u32 need_eq = 819u - cntGT;

  int cnt = 0;
#pragma unroll
  for (int j = 0; j < 16; ++j) cnt += (kreg[j] == vkey) ? 1 : 0;
  u32 inc = (u32)cnt;
#pragma unroll
  for (int o = 1; o < 64; o <<= 1) {
    u32 nv = __shfl_up(inc, o, 64);
    if (lane >= o) inc += nv;
  }
  u32 run = inc - (u32)cnt;

  u16 ov[16];
#pragma unroll
  for (int j = 0; j < 16; ++j) {
    u32 kk = kreg[j];
    bool eq = (kk == vkey);
    bool keep = (kk > vkey) || (eq && (run < need_eq));
    if (eq) run += 1u;
    ov[j] = keep ? f2bf(__uint_as_float(kk)) : (u16)0;
  }
  u16* arow = adj + ((size_t)(b0 + g) * 1024 + n) * 1024 + e0;
  *(uint4*)&arow[0] = *(uint4*)&ov[0];
  *(uint4*)&arow[8] = *(uint4*)&ov[8];
}

// K4 v3: agg = adj @ vr, bf16 MFMA 16x16x32. 256x256 tile, 512 threads,
// 8 waves each owning a 128x64 sub-tile (acc[8][4]). Panel re-reads drop
// A x6/B x8 -> A x3/B x4: 384 -> 192 MB total traffic. Same fragments, same
// kt-ascending accumulation -> agg bit-identical. 192 blocks (<=1/CU, no
// tail). Padded-40 LDS stride (proven conflict pattern). No min-occ bound.
__global__ __launch_bounds__(512) void k_gemm_agg(
    const u16* __restrict__ adj, const u16* __restrict__ vrT, float* __restrict__ agg)
{
  __shared__ u16 As[256 * 40];
  __shared__ u16 Bs[256 * 40];
  const int tid = threadIdx.x;
  const int b = blockIdx.z;
  const int n0 = blockIdx.y * 256;
  const int ct0 = blockIdx.x * 256;
  const int wid = tid >> 6;
  const int lane = tid & 63;
  const int l16 = lane & 15;
  const int quad = lane >> 4;
  const int wm = (wid >> 2) * 128;   // 0 / 128
  const int wn = (wid & 3) * 64;     // 0 / 64 / 128 / 192

  f32x4 acc[8][4];
#pragma unroll
  for (int i = 0; i < 8; ++i)
#pragma unroll
    for (int j = 0; j < 4; ++j) acc[i][j] = (f32x4)0.f;

  const u16* aG = adj + ((size_t)b * 1024 + n0) * 1024;
  const u16* bG = vrT + ((size_t)b * 768 + ct0) * 1024;

  for (int kt = 0; kt < 32; ++kt) {
    const int k0 = kt * 32;
    __syncthreads();
#pragma unroll
    for (int j = 0; j < 2; ++j) {
      int idx = tid + 512 * j;
      int row = idx >> 2, seg = idx & 3;
      *(uint4*)&As[row * 40 + seg * 8] = *(const uint4*)&aG[(size_t)row * 1024 + k0 + seg * 8];
      *(uint4*)&Bs[row * 40 + seg * 8] = *(const uint4*)&bG[(size_t)row * 1024 + k0 + seg * 8];
    }
    __syncthreads();
    bf16x8 af[8], bfv[4];
#pragma unroll
    for (int i = 0; i < 8; ++i) af[i] = *(bf16x8*)&As[(wm + i * 16 + l16) * 40 + quad * 8];
#pragma unroll
    for (int j = 0; j < 4; ++j) bfv[j] = *(bf16x8*)&Bs[(wn + j * 16 + l16) * 40 + quad * 8];
#pragma unroll
    for (int i = 0; i < 8; ++i)
#pragma unroll
      for (int j = 0; j < 4; ++j)
        acc[i][j] = __builtin_amdgcn_mfma_f32_16x16x32_bf16(af[i], bfv[j], acc[i][j], 0, 0, 0);
  }

#pragma unroll
  for (int i = 0; i < 8; ++i)
#pragma unroll
    for (int j = 0; j < 4; ++j)
#pragma unroll
      for (int r = 0; r < 4; ++r) {
        int row = n0 + wm + i * 16 + quad * 4 + r;
        int col = ct0 + wn + j * 16 + l16;
        agg[((size_t)b * 1024 + row) * 768 + col] = acc[i][j][r];
      }
}

// K5: out = relu(conv_c(agg)), fp32
__global__ __launch_bounds__(256) void k_convc(
    const float* __restrict__ agg, const float* __restrict__ cw,
    const float* __restrict__ cb, float* __restrict__ out)
{
  __shared__ float aggL[16 * 388];
  __shared__ float cwT[64 * 68];
  __shared__ float cbL[64];
  const int tid = threadIdx.x;
  const int b = blockIdx.y;
  const int n0 = blockIdx.x * 16;

#pragma unroll
  for (int j = 0; j < 16; ++j) {
    int idx = tid + 256 * j;
    int o = idx >> 6, c = idx & 63;
    cwT[c * 68 + o] = cw[idx];
  }
  if (tid < 64) cbL[tid] = cb[tid];

  const int o0 = (tid & 15) * 4;
  const int nl = tid >> 4;
  float acc[4][12];
#pragma unroll
  for (int oo = 0; oo < 4; ++oo)
#pragma unroll
    for (int t = 0; t < 12; ++t) acc[oo][t] = 0.f;

  for (int ph = 0; ph < 2; ++ph) {
    __syncthreads();
#pragma unroll
    for (int j = 0; j < 6; ++j) {
      int q4 = tid + 256 * j;
      int row = q4 / 96, wi = q4 - row * 96;
      *(float4*)&aggL[row * 388 + wi * 4] =
          *(const float4*)&agg[((size_t)(b * 1024 + n0 + row)) * 768 + ph * 384 + wi * 4];
    }
    __syncthreads();
    for (int cc = 0; cc < 32; ++cc) {
      int c = ph * 32 + cc;
      float4 w4 = *(float4*)&cwT[c * 68 + o0];
      float xr[12];
      *(float4*)&xr[0] = *(float4*)&aggL[nl * 388 + cc * 12 + 0];
      *(float4*)&xr[4] = *(float4*)&aggL[nl * 388 + cc * 12 + 4];
      *(float4*)&xr[8] = *(float4*)&aggL[nl * 388 + cc * 12 + 8];
#pragma unroll
      for (int t = 0; t < 12; ++t) {
        acc[0][t] += w4.x * xr[t];
        acc[1][t] += w4.y * xr[t];
        acc[2][t] += w4.z * xr[t];
        acc[3][t] += w4.w * xr[t];
      }
    }
  }

#pragma unroll
  for (int oo = 0; oo < 4; ++oo) {
    int o = o0 + oo;
    float bias = cbL[o];
    float ovv[12];
#pragma unroll
    for (int t = 0; t < 12; ++t) ovv[t] = fmaxf(acc[oo][t] + bias, 0.f);
    size_t base = ((size_t)(b * 64 + o) * 1024 + n0 + nl) * 12;
    *(float4*)&out[base + 0] = *(float4*)&ovv[0];
    *(float4*)&out[base + 4] = *(float4*)&ovv[4];
    *(float4*)&out[base + 8] = *(float4*)&ovv[8];
  }
}

extern "C" void kernel_launch(void* const* d_in, const int* in_sizes, int n_in,
                              void* d_out, int out_size, void* d_ws, size_t ws_size,
                              hipStream_t stream)
{
  const float* x    = (const float*)d_in[0];
  const float* qw   = (const float*)d_in[1];
  const float* qb   = (const float*)d_in[2];
  const float* vw   = (const float*)d_in[3];
  const float* vb   = (const float*)d_in[4];
  const float* cw   = (const float*)d_in[5];
  const float* cb   = (const float*)d_in[6];
  const float* mem  = (const float*)d_in[7];
  const float* fc1w = (const float*)d_in[8];
  const float* fc1b = (const float*)d_in[9];
  const float* fc2w = (const float*)d_in[10];
  const float* fc2b = (const float*)d_in[11];
  float* out = (float*)d_out;
  char* ws = (char*)d_ws;

  const size_t szQS64  = (size_t)16 * 1024 * 64 * 8;   // 8 MB
  const size_t szQS32T = (size_t)16 * 1024 * 64 * 4;   // 4 MB
  const size_t szVR    = (size_t)16 * 1024 * 768 * 2;  // 24 MB
  const size_t szADJ   = (size_t)16 * 1024 * 1024 * 2; // 32 MB
  const size_t szAGG   = (size_t)16 * 1024 * 768 * 4;  // 48 MB
  const size_t szWT    = (size_t)2 * 64 * 64 * 4;      // 32 KB (wqT + wvT)
  const size_t szSb    = (size_t)1024 * 1024 * 4;      // one f32 S matrix, one batch
  const size_t fixed   = szQS64 + szQS32T + 2 * szVR + szADJ + szAGG + szWT;

  int G = 16;
  while (G > 1 && (fixed + (size_t)2 * G * szSb) > ws_size) G >>= 1;

  double* qs64  = (double*)(ws);
  float*  qs32T = (float*)(ws + szQS64);
  u16*  vr      = (u16*)(ws + szQS64 + szQS32T);
  u16*  vrT     = (u16*)(ws + szQS64 + szQS32T + szVR);
  u16*  adj     = (u16*)(ws + szQS64 + szQS32T + 2 * szVR);
  float* agg    = (float*)(ws + szQS64 + szQS32T + 2 * szVR + szADJ);
  float* wqTg   = (float*)(ws + szQS64 + szQS32T + 2 * szVR + szADJ + szAGG);
  float* wvTg   = wqTg + 64 * 64;
  float* S1     = (float*)(ws + fixed);
  float* S2     = S1 + (size_t)G * 1024 * 1024;

  hipLaunchKernelGGL(k_wT, dim3(4), dim3(1024), 0, stream, qw, vw, wqTg, wvTg);
  hipLaunchKernelGGL(k_conv_qv, dim3(128, 16), dim3(512), 0, stream, x, wqTg, qb, wvTg, vb, qs64, qs32T, vr);
  hipLaunchKernelGGL(k_transpose_vr, dim3(12, 16, 16), dim3(256), 0, stream, vr, vrT);
  for (int b0 = 0; b0 < 16; b0 += G) {
    hipLaunchKernelGGL(k_score, dim3(16, 8, G), dim3(256), 0, stream, qs64, qs32T, mem, S1, S2, b0);
    hipLaunchKernelGGL(k_row, dim3(256, G), dim3(256), 0, stream, S1, S2, fc1w, fc1b, fc2w, fc2b, adj, b0);
  }
  hipLaunchKernelGGL(k_gemm_agg, dim3(3, 4, 16), dim3(512), 0, stream, adj, vrT, agg);
  hipLaunchKernelGGL(k_convc, dim3(64, 16), dim3(256), 0, stream, agg, cw, cb, out);
}